// Round 6
// baseline (42.004 us; speedup 1.0000x reference)
//
#include <hip/hip_runtime.h>
#include <math.h>

#define N_  4
#define C_  3
#define H_  540
#define W_  960
#define HO_ 1080
#define WO_ 1920

typedef float f32x4 __attribute__((ext_vector_type(4)));

// Thread = (n, c, ly, tx8): owns low-res cols [8tx8, 8tx8+8), output rows
// {2ly, 2ly+1}, output cols [16tx8, 16tx8+16) -> 32 output px, 8 f32x4 stores.
// Window proof: ix(ox) = ox/2 + 0.25 - jx -> x0 in {m-1, m}, m = ox>>1;
//               iy(oy) = oy/2 + 0.25 - jy -> y0 in {ly-1, ly}; z row == ly.
// Clamped window loads make border-excluded 3x3 pools == plain min/max over the
// clamped 3x10 window (duplicates never change min/max).
//
// R3: bijective chunked XCD swizzle (T1): +10% (33.2 -> 30.0 us).
// R5: nontemporal stores REGRESSED (30.0 -> 33.7): L2/L3 absorbs the 99.5 MB
//     write stream (output fits in 256 MiB L3); nt forfeits that. Reverted.
// R6: 8-col tiles: 12 load insts (vs 18 per equivalent), half the waves,
//     grid-const math amortized 2x; plain float4 stores; keep VALU trim.
__global__ __launch_bounds__(256) void taa_fused_kernel(
    const float* __restrict__ frame,
    const float* __restrict__ jitter,
    float* __restrict__ out,
    int total_threads, int n_blocks, long long out_elems)
{
    // ---- bijective chunked XCD swizzle (nwg = n_blocks, 8 XCDs)
    int b   = blockIdx.x;
    int q   = n_blocks >> 3, r = n_blocks & 7;
    int xcd = b & 7, i = b >> 3;
    int wb  = (xcd < r ? xcd * (q + 1) : r * (q + 1) + (xcd - r) * q) + i;

    int idx = wb * 256 + threadIdx.x;
    if (idx >= total_threads) return;

    const int TX = W_ / 8;   // 120
    int tx  = idx % TX;
    int t   = idx / TX;
    int ly  = t % H_;
    int nc  = t / H_;            // n*C_ + c  in [0,12)
    int n   = nc / C_;
    int lx0 = tx * 8;

    float jx = jitter[2 * n + 0];
    float jy = jitter[2 * n + 1];
    int jnx = (int)floorf(jx * 2.0f);
    int jny = (int)floorf(jy * 2.0f);
    int bjx = (int)floorf(jitter[0] * 2.0f);   // beta lattice uses batch-0 jitter
    int bjy = (int)floorf(jitter[1] * 2.0f);
    bool zcoin = (jnx == bjx) && (jny == bjy); // z-lattice coincides with beta-lattice

    const float* fp = frame + (size_t)nc * (H_ * W_);

    int r0 = (ly > 0)          ? ly - 1   : 0;
    int r2 = (ly < H_ - 1)     ? ly + 1   : H_ - 1;
    int cL = (lx0 > 0)         ? lx0 - 1  : 0;
    int cR = (lx0 + 8 < W_)    ? lx0 + 8  : W_ - 1;

    // ---- 3x10 clamped window (12 load instructions)
    float w0[10], w1[10], w2[10];
    {
        const float* rp = fp + r0 * W_;
        f32x4 a = *(const f32x4*)(rp + lx0);
        f32x4 c = *(const f32x4*)(rp + lx0 + 4);
        w0[0]=rp[cL]; w0[1]=a.x; w0[2]=a.y; w0[3]=a.z; w0[4]=a.w;
        w0[5]=c.x; w0[6]=c.y; w0[7]=c.z; w0[8]=c.w; w0[9]=rp[cR];
        rp = fp + ly * W_;
        a = *(const f32x4*)(rp + lx0);
        c = *(const f32x4*)(rp + lx0 + 4);
        w1[0]=rp[cL]; w1[1]=a.x; w1[2]=a.y; w1[3]=a.z; w1[4]=a.w;
        w1[5]=c.x; w1[6]=c.y; w1[7]=c.z; w1[8]=c.w; w1[9]=rp[cR];
        rp = fp + r2 * W_;
        a = *(const f32x4*)(rp + lx0);
        c = *(const f32x4*)(rp + lx0 + 4);
        w2[0]=rp[cL]; w2[1]=a.x; w2[2]=a.y; w2[3]=a.z; w2[4]=a.w;
        w2[5]=c.x; w2[6]=c.y; w2[7]=c.z; w2[8]=c.w; w2[9]=rp[cR];
    }

    // ---- 3x3 min/max pools for the 8 low-res cols (column partials first)
    float cmax[10], cmin[10];
    #pragma unroll
    for (int j = 0; j < 10; ++j) {
        cmax[j] = fmaxf(fmaxf(w0[j], w1[j]), w2[j]);
        cmin[j] = fminf(fminf(w0[j], w1[j]), w2[j]);
    }
    float vmax[8], vmin[8];
    #pragma unroll
    for (int p = 0; p < 8; ++p) {
        vmax[p] = fmaxf(fmaxf(cmax[p], cmax[p+1]), cmax[p+2]);
        vmin[p] = fminf(fminf(cmin[p], cmin[p+1]), cmin[p+2]);
    }

    // ---- x-grid constants per output-column parity (exact reference op order)
    float wx_[2]; bool dxm1_[2];
    #pragma unroll
    for (int par = 0; par < 2; ++par) {
        int ox = 16 * tx + par;
        float xs = (2.0f * (float)ox + 1.0f) / (float)WO_ - 1.0f;
        float gx = xs + 2.0f * (0.5f - jx) / (float)W_;
        float ix = ((gx + 1.0f) * (float)W_ - 1.0f) / 2.0f;
        float x0f = floorf(ix);
        wx_[par]   = ix - x0f;
        dxm1_[par] = ((int)x0f < lx0);   // x0 = m-1 (window shift) vs m
    }

    size_t base = (size_t)nc * ((size_t)HO_ * WO_);

    #pragma unroll
    for (int ry = 0; ry < 2; ++ry) {
        int oy = 2 * ly + ry;
        float ysv = (2.0f * (float)oy + 1.0f) / (float)HO_ - 1.0f;
        float gy = ysv + 2.0f * (0.5f - jy) / (float)H_;
        float iy = ((gy + 1.0f) * (float)H_ - 1.0f) / 2.0f;
        float y0f = floorf(iy);
        float wy  = iy - y0f;
        bool up = ((int)y0f < ly);   // y0 row = ly-1 (window row0) else ly (row1)

        // y-blend first (wy, up are image-uniform; FP reorder vs ref is ~1 ulp)
        float brow[10];
        #pragma unroll
        for (int j = 0; j < 10; ++j) {
            float t0 = up ? w0[j] : w1[j];
            float t1 = up ? w1[j] : w2[j];
            brow[j] = t0 + wy * (t1 - t0);
        }
        // parity-shifted 9-wide views: s[j] = brow[j + (dm ? 0 : 1)]
        float s0[9], s1[9];
        #pragma unroll
        for (int j = 0; j < 9; ++j) {
            s0[j] = dxm1_[0] ? brow[j] : brow[j + 1];
            s1[j] = dxm1_[1] ? brow[j] : brow[j + 1];
        }

        float res[16];
        #pragma unroll
        for (int rx = 0; rx < 16; ++rx) {
            const int par  = rx & 1;   // compile-time after unroll
            const int bcol = rx >> 1;
            float v0 = par ? s1[bcol]     : s0[bcol];
            float v1 = par ? s1[bcol + 1] : s0[bcol + 1];
            float bil = v0 + wx_[par] * (v1 - v0);
            float h = fminf(vmax[bcol], bil);
            h = fmaxf(vmin[bcol], h);
            bool isb = (ry == bjy) && (par == bjx);
            float zv = zcoin ? w1[bcol + 1] : 0.0f;
            res[rx] = isb ? (0.1f * zv + (1.0f - 0.1f) * h) : h;
        }

        size_t off = base + (size_t)oy * WO_ + (size_t)16 * tx;
        if ((long long)(off + 16) <= out_elems) {   // defensive: never write OOB
            f32x4 o0 = { res[0],  res[1],  res[2],  res[3]  };
            f32x4 o1 = { res[4],  res[5],  res[6],  res[7]  };
            f32x4 o2 = { res[8],  res[9],  res[10], res[11] };
            f32x4 o3 = { res[12], res[13], res[14], res[15] };
            *(f32x4*)(out + off)      = o0;
            *(f32x4*)(out + off + 4)  = o1;
            *(f32x4*)(out + off + 8)  = o2;
            *(f32x4*)(out + off + 12) = o3;
        }
    }
}

extern "C" void kernel_launch(void* const* d_in, const int* in_sizes, int n_in,
                              void* d_out, int out_size, void* d_ws, size_t ws_size,
                              hipStream_t stream) {
    const float* frame  = (const float*)d_in[0];
    const float* jitter = (const float*)d_in[1];
    float* out = (float*)d_out;

    const int total = N_ * C_ * H_ * (W_ / 8);   // 777,600 threads, 32 px each
    const int block = 256;
    const int grid  = (total + block - 1) / block;  // 3038 blocks
    taa_fused_kernel<<<grid, block, 0, stream>>>(frame, jitter, out,
                                                 total, grid, (long long)out_size);
}

// Round 7
// 27.975 us; speedup vs baseline: 1.5015x; 1.5015x over previous
//
#include <hip/hip_runtime.h>
#include <math.h>

#define N_  4
#define C_  3
#define H_  540
#define W_  960
#define HO_ 1080
#define WO_ 1920

typedef float f32x4 __attribute__((ext_vector_type(4)));

// Thread = (n, c, ly, tx): owns low-res cols [4tx, 4tx+4), output rows {2ly, 2ly+1},
// output cols [8tx, 8tx+8) -> 16 output px, 4 f32x4 stores.
// Window proof: ix(ox) = ox/2 + 0.25 - jx -> x0 in {m-1, m}, m = ox>>1;
//               iy(oy) = oy/2 + 0.25 - jy -> y0 in {ly-1, ly}; z row == ly.
// Clamped window loads make border-excluded 3x3 pools == plain min/max over the
// clamped 3x6 window (duplicates never change min/max).
//
// Ladder: R2 naive-fused 33.2 | R3 +XCD swizzle 30.0 | R5 +nt stores 33.7
// (REGRESSED - L2/L3 absorbs the write stream; reverted) | R6 8-col tile 42.0
// (REGRESSED - VGPR/occupancy cliff; reverted).
// R7: R3 base + isolated VALU trim: y-blend first into brow[6], parity-shifted
// 5-wide views (x-tap offset is image-uniform), 1 lerp per pixel. Fewer live
// regs than R3's per-pixel 4-tap cndmask cascade.
__global__ __launch_bounds__(256) void taa_fused_kernel(
    const float* __restrict__ frame,
    const float* __restrict__ jitter,
    float* __restrict__ out,
    int total_threads, int n_blocks, long long out_elems)
{
    // ---- bijective chunked XCD swizzle (nwg = n_blocks, 8 XCDs)
    int b   = blockIdx.x;
    int q   = n_blocks >> 3, r = n_blocks & 7;
    int xcd = b & 7, i = b >> 3;
    int wb  = (xcd < r ? xcd * (q + 1) : r * (q + 1) + (xcd - r) * q) + i;

    int idx = wb * 256 + threadIdx.x;
    if (idx >= total_threads) return;

    const int TX = W_ / 4;   // 240
    int tx  = idx % TX;
    int t   = idx / TX;
    int ly  = t % H_;
    int nc  = t / H_;            // n*C_ + c  in [0,12)
    int n   = nc / C_;
    int lx0 = tx * 4;

    float jx = jitter[2 * n + 0];
    float jy = jitter[2 * n + 1];
    int jnx = (int)floorf(jx * 2.0f);
    int jny = (int)floorf(jy * 2.0f);
    int bjx = (int)floorf(jitter[0] * 2.0f);   // beta lattice uses batch-0 jitter
    int bjy = (int)floorf(jitter[1] * 2.0f);
    bool zcoin = (jnx == bjx) && (jny == bjy); // z-lattice coincides with beta-lattice

    const float* fp = frame + (size_t)nc * (H_ * W_);

    int r0 = (ly > 0)          ? ly - 1   : 0;
    int r2 = (ly < H_ - 1)     ? ly + 1   : H_ - 1;
    int cL = (lx0 > 0)         ? lx0 - 1  : 0;
    int cR = (lx0 + 4 < W_)    ? lx0 + 4  : W_ - 1;

    // ---- 3x6 clamped window (9 load instructions)
    float w0[6], w1[6], w2[6];
    {
        const float* rp = fp + r0 * W_;
        f32x4 m = *(const f32x4*)(rp + lx0);
        w0[0]=rp[cL]; w0[1]=m.x; w0[2]=m.y; w0[3]=m.z; w0[4]=m.w; w0[5]=rp[cR];
        rp = fp + ly * W_;
        m = *(const f32x4*)(rp + lx0);
        w1[0]=rp[cL]; w1[1]=m.x; w1[2]=m.y; w1[3]=m.z; w1[4]=m.w; w1[5]=rp[cR];
        rp = fp + r2 * W_;
        m = *(const f32x4*)(rp + lx0);
        w2[0]=rp[cL]; w2[1]=m.x; w2[2]=m.y; w2[3]=m.z; w2[4]=m.w; w2[5]=rp[cR];
    }

    // ---- 3x3 min/max pools for the 4 low-res cols (column partials first)
    float cmax[6], cmin[6];
    #pragma unroll
    for (int j = 0; j < 6; ++j) {
        cmax[j] = fmaxf(fmaxf(w0[j], w1[j]), w2[j]);
        cmin[j] = fminf(fminf(w0[j], w1[j]), w2[j]);
    }
    float vmax[4], vmin[4];
    #pragma unroll
    for (int p = 0; p < 4; ++p) {
        vmax[p] = fmaxf(fmaxf(cmax[p], cmax[p+1]), cmax[p+2]);
        vmin[p] = fminf(fminf(cmin[p], cmin[p+1]), cmin[p+2]);
    }

    // ---- x-grid constants per output-column parity (exact reference op order)
    float wx_[2]; bool dxm1_[2];
    #pragma unroll
    for (int par = 0; par < 2; ++par) {
        int ox = 8 * tx + par;
        float xs = (2.0f * (float)ox + 1.0f) / (float)WO_ - 1.0f;
        float gx = xs + 2.0f * (0.5f - jx) / (float)W_;
        float ix = ((gx + 1.0f) * (float)W_ - 1.0f) / 2.0f;
        float x0f = floorf(ix);
        wx_[par]   = ix - x0f;
        dxm1_[par] = ((int)x0f < lx0);   // x0 = m-1 (window shift) vs m
    }

    size_t base = (size_t)nc * ((size_t)HO_ * WO_);

    #pragma unroll
    for (int ry = 0; ry < 2; ++ry) {
        int oy = 2 * ly + ry;
        float ysv = (2.0f * (float)oy + 1.0f) / (float)HO_ - 1.0f;
        float gy = ysv + 2.0f * (0.5f - jy) / (float)H_;
        float iy = ((gy + 1.0f) * (float)H_ - 1.0f) / 2.0f;
        float y0f = floorf(iy);
        float wy  = iy - y0f;
        bool up = ((int)y0f < ly);   // y0 row = ly-1 (window row0) else ly (row1)

        // y-blend first (wy, up are image-uniform; FP reorder vs ref is ~1 ulp)
        float brow[6];
        #pragma unroll
        for (int j = 0; j < 6; ++j) {
            float t0 = up ? w0[j] : w1[j];
            float t1 = up ? w1[j] : w2[j];
            brow[j] = t0 + wy * (t1 - t0);
        }
        // parity-shifted 5-wide views: s[j] = brow[j + (dm ? 0 : 1)]
        float s0[5], s1[5];
        #pragma unroll
        for (int j = 0; j < 5; ++j) {
            s0[j] = dxm1_[0] ? brow[j] : brow[j + 1];
            s1[j] = dxm1_[1] ? brow[j] : brow[j + 1];
        }

        float res[8];
        #pragma unroll
        for (int rx = 0; rx < 8; ++rx) {
            const int par  = rx & 1;   // compile-time after unroll
            const int bcol = rx >> 1;
            float v0 = par ? s1[bcol]     : s0[bcol];
            float v1 = par ? s1[bcol + 1] : s0[bcol + 1];
            float bil = v0 + wx_[par] * (v1 - v0);
            float h = fminf(vmax[bcol], bil);
            h = fmaxf(vmin[bcol], h);
            bool isb = (ry == bjy) && (par == bjx);
            float zv = zcoin ? w1[bcol + 1] : 0.0f;
            res[rx] = isb ? (0.1f * zv + (1.0f - 0.1f) * h) : h;
        }

        size_t off = base + (size_t)oy * WO_ + (size_t)8 * tx;
        if ((long long)(off + 8) <= out_elems) {   // defensive: never write OOB
            f32x4 lo = { res[0], res[1], res[2], res[3] };
            f32x4 hi = { res[4], res[5], res[6], res[7] };
            *(f32x4*)(out + off)     = lo;
            *(f32x4*)(out + off + 4) = hi;
        }
    }
}

extern "C" void kernel_launch(void* const* d_in, const int* in_sizes, int n_in,
                              void* d_out, int out_size, void* d_ws, size_t ws_size,
                              hipStream_t stream) {
    const float* frame  = (const float*)d_in[0];
    const float* jitter = (const float*)d_in[1];
    float* out = (float*)d_out;

    const int total = N_ * C_ * H_ * (W_ / 4);   // 1,555,200 threads, 16 px each
    const int block = 256;
    const int grid  = (total + block - 1) / block;  // 6075 blocks
    taa_fused_kernel<<<grid, block, 0, stream>>>(frame, jitter, out,
                                                 total, grid, (long long)out_size);
}